// Round 1
// baseline (595.210 us; speedup 1.0000x reference)
//
#include <hip/hip_runtime.h>
#include <stdint.h>

#define Bsz   256
#define Tlen  1024
#define Vocab 128
#define Hdim  128
#define NTHR  512
#define WTN   ((Vocab - 1) * Hdim)   // 127*128 = 16256 floats

typedef _Float16 half2_t __attribute__((ext_vector_type(2)));

__device__ __forceinline__ float tanh_fast(float x) {
    // tanh(x) = 1 - 2/(exp2(2x*log2e)+1); exact limits at +-inf
    float e = __builtin_amdgcn_exp2f(x * 2.885390081777927f);
    return 1.0f - 2.0f * __builtin_amdgcn_rcpf(e + 1.0f);
}

__device__ __forceinline__ float dpp_xor1(float s) {
    return __int_as_float(__builtin_amdgcn_mov_dpp(__float_as_int(s), 0xB1, 0xF, 0xF, true));  // quad_perm(1,0,3,2)
}

// Prep: transpose W_ih (H x V-1) -> wtb (V-1 x H) with bias folded in:
// wtb[f][h] = W_ih[h][f] + b_ih[h] + b_hh[h]  (pre-table used once per step)
__global__ __launch_bounds__(256) void prep_kernel(
    const float* __restrict__ W_ih, const float* __restrict__ b_ih,
    const float* __restrict__ b_hh, float* __restrict__ wtb)
{
    int idx = blockIdx.x * 256 + threadIdx.x;
    if (idx < WTN) {
        int h = idx / (Vocab - 1);
        int f = idx - h * (Vocab - 1);
        wtb[f * Hdim + h] = W_ih[idx] + b_ih[h] + b_hh[h];
    }
}

// One block per sequence. All 8 waves stage wt + decode symbols; then waves
// 1-7 exit and wave 0 runs the entire recurrence with ZERO barriers:
//   lane l=(g=l>>1, j=l&1) owns outputs {4g+2j, 4g+2j+1}, K-half [64j,64j+64)
//   W_hh rows {mine0, mine1, partner0, partner1} pinned as 128 f16x2 VGPRs
//   per step: 8 broadcast ds_read_b128 of h, 128 fdot2 (4 chains x 32),
//   one dpp_xor1 pair-exchange, tanh x2, one ds_write_b32 per lane.
// Same-wave DS ops execute in order -> write->read needs no barrier.
__global__ __launch_bounds__(NTHR, 2) void rnn_kernel(
    const float* __restrict__ x, const float* __restrict__ wtb,
    const float* __restrict__ W_hh, const float* __restrict__ W_out,
    const float* __restrict__ b_out, float* __restrict__ out)
{
    __shared__ float wt_s[WTN];                    // 65 KB pre-gather table
    __shared__ int   syms[Tlen];                   // 4 KB
    __shared__ __align__(16) int hbuf[Hdim / 2];   // 64 dwords = 128 f16 h
    __shared__ int   len_sh;

    const int tid = threadIdx.x;
    const int b   = blockIdx.x;

    if (tid == 0) len_sh = Tlen;
    if (tid < Hdim / 2) hbuf[tid] = 0;             // h0 = 0

    // stage wtb -> LDS, coalesced float4
    {
        const float4* src = (const float4*)wtb;
        float4* dst = (float4*)wt_s;
        for (int k = tid; k < WTN / 4; k += NTHR) dst[k] = src[k];
    }

    // Decode this block's one-hot rows (512 KB contiguous, float4 coalesced).
    const float4* xb = (const float4*)(x + (size_t)b * Tlen * Vocab);
    for (int k = tid; k < (Tlen * Vocab) / 4; k += NTHR) {
        float4 v = xb[k];
        int c = -1;
        if      (v.x > 0.5f) c = 0;
        else if (v.y > 0.5f) c = 1;
        else if (v.z > 0.5f) c = 2;
        else if (v.w > 0.5f) c = 3;
        if (c >= 0) syms[k >> 5] = ((k & 31) << 2) + c;  // 32 float4 per row
    }
    __syncthreads();

    // length = first t with sym==0 (pad), else Tlen
    {
        int lm = Tlen;
        for (int k = tid; k < Tlen; k += NTHR)
            if (syms[k] == 0 && k < lm) lm = k;
        if (lm < Tlen) atomicMin(&len_sh, lm);
    }
    __syncthreads();
    const int len = len_sh;

    if (tid >= 64) return;   // only wave 0 runs the recurrence

    const int l = tid;       // lane 0..63
    const int g = l >> 1;    // group: outputs 4g..4g+3
    const int j = l & 1;     // K-half: h[64j .. 64j+63]

    // W_hh rows, slots {my0, my1, partner0, partner1}, cols [64j, 64j+64)
    int wp[128];
    {
        const int rows[4] = {4 * g + 2 * j, 4 * g + 2 * j + 1,
                             4 * g + 2 - 2 * j, 4 * g + 3 - 2 * j};
        #pragma unroll
        for (int rs = 0; rs < 4; rs++) {
            const float4* wrow = (const float4*)(W_hh + rows[rs] * Hdim + 64 * j);
            #pragma unroll
            for (int q = 0; q < 16; q++) {
                float4 t4 = wrow[q];
                wp[rs * 32 + 2 * q]     = __builtin_bit_cast(int, __builtin_amdgcn_cvt_pkrtz(t4.x, t4.y));
                wp[rs * 32 + 2 * q + 1] = __builtin_bit_cast(int, __builtin_amdgcn_cvt_pkrtz(t4.z, t4.w));
            }
        }
    }

    // pre pipeline: float2 index = (sym-1)*64 + l  -> floats (sym-1)*128 + 2l
    // = pre for outputs {4g+2j, 4g+2j+1} == exactly this lane's outputs.
    const float2* wt2 = (const float2*)wt_s;
    float2 pre_v = {0.0f, 0.0f}, p_t1 = {0.0f, 0.0f};
    int s_t2 = 1;
    if (len > 0) pre_v = wt2[(syms[0] - 1) * 64 + l];
    if (len > 1) p_t1  = wt2[(syms[1] - 1) * 64 + l];
    if (len > 2) s_t2  = syms[2];

    const char* hbp = (const char*)hbuf + 128 * j;

    for (int t = 0; t < len; t++) {
        // Pin packed W in VGPRs every iteration (opaque redefinition blocks
        // rematerialization / sinking of the global W loads into the loop).
        #pragma unroll
        for (int k = 0; k < 128; k += 8)
            asm volatile("" : "+v"(wp[k]), "+v"(wp[k+1]), "+v"(wp[k+2]), "+v"(wp[k+3]),
                              "+v"(wp[k+4]), "+v"(wp[k+5]), "+v"(wp[k+6]), "+v"(wp[k+7]));

        float2 p_t2 = wt2[(s_t2 - 1) * 64 + l];   // gather pre for t+2
        int   s_t3 = (t + 3 < len) ? syms[t + 3] : 1;

        // h[t]: lanes with equal j read identical addresses -> broadcast
        uint4 q0 = *(const uint4*)(hbp);
        uint4 q1 = *(const uint4*)(hbp + 16);
        uint4 q2 = *(const uint4*)(hbp + 32);
        uint4 q3 = *(const uint4*)(hbp + 48);
        uint4 q4 = *(const uint4*)(hbp + 64);
        uint4 q5 = *(const uint4*)(hbp + 80);
        uint4 q6 = *(const uint4*)(hbp + 96);
        uint4 q7 = *(const uint4*)(hbp + 112);
        unsigned hr[32] = {q0.x, q0.y, q0.z, q0.w, q1.x, q1.y, q1.z, q1.w,
                           q2.x, q2.y, q2.z, q2.w, q3.x, q3.y, q3.z, q3.w,
                           q4.x, q4.y, q4.z, q4.w, q5.x, q5.y, q5.z, q5.w,
                           q6.x, q6.y, q6.z, q6.w, q7.x, q7.y, q7.z, q7.w};

        // 4 chains x 32 fdot2; pre+bias injected as accumulator init of the
        // two chains this lane finalizes (partner chains start at 0).
        float a0 = pre_v.x, a1 = pre_v.y, a2 = 0.0f, a3 = 0.0f;
        #pragma unroll
        for (int d = 0; d < 32; d++) {
            half2_t hh = __builtin_bit_cast(half2_t, hr[d]);
            a0 = __builtin_amdgcn_fdot2(hh, __builtin_bit_cast(half2_t, wp[d]),       a0, false);
            a1 = __builtin_amdgcn_fdot2(hh, __builtin_bit_cast(half2_t, wp[32 + d]),  a1, false);
            a2 = __builtin_amdgcn_fdot2(hh, __builtin_bit_cast(half2_t, wp[64 + d]),  a2, false);
            a3 = __builtin_amdgcn_fdot2(hh, __builtin_bit_cast(half2_t, wp[96 + d]),  a3, false);
        }
        // partner lane's a2/a3 are the other K-half of MY rows (and vice versa)
        float h0 = tanh_fast(a0 + dpp_xor1(a2));
        float h1 = tanh_fast(a1 + dpp_xor1(a3));
        // dword l = h[2l], h[2l+1]; all 64 lanes write, no branch
        hbuf[l] = __builtin_bit_cast(int, __builtin_amdgcn_cvt_pkrtz(h0, h1));
        pre_v = p_t1; p_t1 = p_t2; s_t2 = s_t3;
    }

    // epilogue: hidden state + softmax head (single wave)
    half2_t hv = __builtin_bit_cast(half2_t, hbuf[l]);
    float h0 = (float)hv.x, h1 = (float)hv.y;
    *(float2*)(out + 2 * Bsz + b * Hdim + 2 * l) = make_float2(h0, h1);

    float p0 = W_out[2 * l] * h0 + W_out[2 * l + 1] * h1;
    float p1 = W_out[Hdim + 2 * l] * h0 + W_out[Hdim + 2 * l + 1] * h1;
    #pragma unroll
    for (int off = 32; off > 0; off >>= 1) {
        p0 += __shfl_down(p0, off, 64);
        p1 += __shfl_down(p1, off, 64);
    }
    if (l == 0) {
        float l0 = p0 + b_out[0], l1 = p1 + b_out[1];
        float m  = fmaxf(l0, l1);
        float e0 = __expf(l0 - m), e1 = __expf(l1 - m);
        float d  = e0 + e1;
        out[b * 2 + 0] = e0 / d;
        out[b * 2 + 1] = e1 / d;
    }
}

extern "C" void kernel_launch(void* const* d_in, const int* in_sizes, int n_in,
                              void* d_out, int out_size, void* d_ws, size_t ws_size,
                              hipStream_t stream) {
    const float* x     = (const float*)d_in[0];
    const float* W_ih  = (const float*)d_in[1];
    const float* W_hh  = (const float*)d_in[2];
    const float* b_ih  = (const float*)d_in[3];
    const float* b_hh  = (const float*)d_in[4];
    const float* W_out = (const float*)d_in[5];
    const float* b_out = (const float*)d_in[6];
    float* out = (float*)d_out;

    float* wtb = (float*)d_ws;  // (V-1) x H floats = 65 KB

    const int NTRN = (WTN + 255) / 256;  // 64 blocks
    prep_kernel<<<NTRN, 256, 0, stream>>>(W_ih, b_ih, b_hh, wtb);
    rnn_kernel<<<Bsz, NTHR, 0, stream>>>(x, wtb, W_hh, W_out, b_out, out);
}